// Round 6
// baseline (219.763 us; speedup 1.0000x reference)
//
#include <hip/hip_runtime.h>
#include <hip/hip_bf16.h>
#include <stdint.h>

#define NASSETS 512
#define WINDOW  256
#define NBATCH  32
#define NWORDS  16      // 512 bits / 32
#define NBLK    512     // grid size; must be <= guaranteed co-resident capacity

typedef __attribute__((ext_vector_type(4))) float floatx4;
typedef __attribute__((ext_vector_type(4))) int   intx4;
typedef __attribute__((ext_vector_type(2))) long  longx2;

// ---- fp32 -> OCP e4m3fn (validated R4/R5: absmax=0) ----
__device__ __forceinline__ unsigned int f2e4m3_manual(float x) {
    union { float f; unsigned u; } c; c.f = x;
    unsigned s = (c.u >> 24) & 0x80u;
    unsigned a = c.u & 0x7FFFFFFFu;
    float af = fabsf(x);
    unsigned code;
    if (af >= 448.f) code = 0x7Eu;
    else if (af < 0.015625f) {
        code = (unsigned)(int)rintf(af * 512.f);
    } else {
        unsigned E = a >> 23;
        unsigned base = ((E - 120u) << 3) | ((a >> 20) & 7u);
        unsigned rem = a & 0xFFFFFu;
        if (rem > 0x80000u || (rem == 0x80000u && (base & 1u))) base++;
        if (base > 0x7Eu) base = 0x7Eu;
        code = base;
    }
    return s | code;
}

__device__ __forceinline__ int pack4fp8(float f0, float f1, float f2, float f3) {
#if defined(__has_builtin) && __has_builtin(__builtin_amdgcn_cvt_pk_fp8_f32)
    int v = 0;
    v = __builtin_amdgcn_cvt_pk_fp8_f32(f0, f1, v, false);
    v = __builtin_amdgcn_cvt_pk_fp8_f32(f2, f3, v, true);
    return v;
#else
    return (int)(f2e4m3_manual(f0) | (f2e4m3_manual(f1) << 8) |
                 (f2e4m3_manual(f2) << 16) | (f2e4m3_manual(f3) << 24));
#endif
}

// async global->LDS, 16B/lane; LDS dst wave-uniform base + lane*16
__device__ __forceinline__ void gload16(const void* gp, void* lp) {
    __builtin_amdgcn_global_load_lds(
        (const __attribute__((address_space(1))) void*)(uintptr_t)gp,
        (__attribute__((address_space(3))) void*)(unsigned int)(uintptr_t)lp,
        16, 0, 0);
}

// FUSED pipeline: phase0 normalize -> bar -> phase1 corr+bitpack -> bar -> phase2 CC.
// 512 blocks x 256 threads; __launch_bounds__(256,2) => worst-case 2 blocks/CU
// (LDS ~20.6KB, VGPR<=256) => capacity >= 512 = grid => barrier cannot deadlock.
__global__ __launch_bounds__(256, 2)
void fused_topo_kernel(const float* __restrict__ ret, char* __restrict__ Xt,
                       unsigned int* __restrict__ adj, int* __restrict__ bar,
                       float* __restrict__ out) {
    __shared__ __align__(16) char smem[16384];   // norm tile(8K) / corr lsA(8K)+lsB(8K)
    __shared__ float sred[256];
    __shared__ float ssred[256];
    __shared__ float smean[32];
    __shared__ float sinv[32];
    __shared__ int lab[NASSETS];
    __shared__ int red[8];
    __shared__ int changed;

    const int t    = threadIdx.x;
    const int blk  = blockIdx.x;
    const int lane = t & 63;
    const int wave = t >> 6;

    // ================= phase 0: normalize -> fp8 Xt (interleaved-slab rows) =====
    {
        const int a  = t & 31;
        const int wc = t >> 5;                 // 0..7, 32 k each
        const int b  = blk >> 4;
        const int n0 = (blk & 15) * 32;
        const float* col = ret + (size_t)b * WINDOW * NASSETS + n0 + a;

        float x[32];
        float s1 = 0.f, s2 = 0.f;
#pragma unroll
        for (int k = 0; k < 32; ++k) {
            x[k] = col[(size_t)(wc * 32 + k) * NASSETS];
            s1 += x[k];
            s2 += x[k] * x[k];
        }
        sred[wc * 32 + a]  = s1;
        ssred[wc * 32 + a] = s2;
        __syncthreads();

        if (t < 32) {
            float S = 0.f, S2 = 0.f;
#pragma unroll
            for (int c = 0; c < 8; ++c) { S += sred[c * 32 + t]; S2 += ssred[c * 32 + t]; }
            float mean = S / (float)WINDOW;
            float var  = (S2 - (float)WINDOW * mean * mean) / (float)(WINDOW - 1);
            if (var < 0.f) var = 0.f;
            float stdv = sqrtf(var) + 1e-8f;   // ref: std(ddof=1) + 1e-8
            smean[t] = mean;
            sinv[t]  = 1.0f / stdv;
        }
        __syncthreads();

        const float mn = smean[a];
        const float iv = sinv[a];

        int pk[8];
#pragma unroll
        for (int j = 0; j < 8; ++j)
            pk[j] = pack4fp8((x[4*j+0] - mn) * iv, (x[4*j+1] - mn) * iv,
                             (x[4*j+2] - mn) * iv, (x[4*j+3] - mn) * iv);

        // row layout: 4 slabs of 64 k; slot q of slab s = k[s*64+q*8..+7] ++ k[s*64+32+q*8..+7]
        char* rowp = smem + a * 256;
        const int s  = wc >> 1;
        const int h8 = (wc & 1) * 8;
#pragma unroll
        for (int q = 0; q < 4; ++q) {
            unsigned long long piece = (unsigned)pk[2*q] |
                                       ((unsigned long long)(unsigned)pk[2*q+1] << 32);
            int L = s * 4 + q;
            *(unsigned long long*)(rowp + ((L ^ (a & 15)) * 16) + h8) = piece;
        }
        __syncthreads();

        char* orow = Xt + ((size_t)b * NASSETS + n0) * WINDOW;
#pragma unroll
        for (int it = 0; it < 2; ++it) {
            int idx = it * 256 + t;
            int r  = idx >> 4;
            int sl = idx & 15;
            intx4 v = *(const intx4*)(smem + r * 256 + ((sl ^ (r & 15)) * 16));
            *(intx4*)(orow + r * WINDOW + sl * 16) = v;
        }
    }

    // ---- grid barrier 0 (release Xt, acquire for corr reads) ----
    __syncthreads();
    if (t == 0) {
        __threadfence();
        __hip_atomic_fetch_add(&bar[0], 1, __ATOMIC_RELEASE, __HIP_MEMORY_SCOPE_AGENT);
        while (__hip_atomic_load(&bar[0], __ATOMIC_ACQUIRE, __HIP_MEMORY_SCOPE_AGENT) < NBLK)
            __builtin_amdgcn_s_sleep(2);
        __threadfence();
    }
    __syncthreads();

    // ================= phase 1: corr (fp8 MFMA) + threshold bit-pack =============
    {
        char* lsA = smem;
        char* lsB = smem + 8192;
        const int b  = blk >> 4;
        const int it = (blk >> 2) & 3;
        const int jt = blk & 3;
        const int i0 = it * 128;
        const int j0 = jt * 128;
        const int wi = wave >> 1, wj = wave & 1;

        const char* base = Xt + (size_t)b * NASSETS * WINDOW;
        const int m  = lane & 15;
        const int kq = lane >> 4;
        const int srowAdd  = lane >> 2;
        const int gslotOff = ((lane & 3) ^ ((lane >> 2) & 3)) * 16;

        floatx4 acc[4][4] = {};

        for (int k0 = 0; k0 < WINDOW; k0 += 64) {
            __syncthreads();
#pragma unroll
            for (int c = 0; c < 2; ++c) {
                int r0 = (wave * 2 + c) * 16;
                const char* gA = base + (size_t)(i0 + r0 + srowAdd) * WINDOW + k0 + gslotOff;
                const char* gB = base + (size_t)(j0 + r0 + srowAdd) * WINDOW + k0 + gslotOff;
                gload16(gA, lsA + r0 * 64);
                gload16(gB, lsB + r0 * 64);
            }
            __syncthreads();

            longx2 af[4], bf[4];
#pragma unroll
            for (int mi = 0; mi < 4; ++mi) {
                int r = wi * 64 + mi * 16 + m;
                af[mi] = *(const longx2*)(lsA + r * 64 + ((kq ^ (r & 3)) * 16));
            }
#pragma unroll
            for (int nj = 0; nj < 4; ++nj) {
                int r = wj * 64 + nj * 16 + m;
                bf[nj] = *(const longx2*)(lsB + r * 64 + ((kq ^ (r & 3)) * 16));
            }
#pragma unroll
            for (int mi = 0; mi < 4; ++mi)
#pragma unroll
                for (int nj = 0; nj < 4; ++nj) {
                    acc[mi][nj] = __builtin_amdgcn_mfma_f32_16x16x32_fp8_fp8(
                        af[mi].x, bf[nj].x, acc[mi][nj], 0, 0, 0);
                    acc[mi][nj] = __builtin_amdgcn_mfma_f32_16x16x32_fp8_fp8(
                        af[mi].y, bf[nj].y, acc[mi][nj], 0, 0, 0);
                }
        }

        // ballot bit-pack (validated). C/D: col=lane&15, row=(lane>>4)*4+r.
        const float T[3] = {0.3f * (float)WINDOW, 0.5f * (float)WINDOW, 0.7f * (float)WINDOW};
        unsigned int wout[3][2] = {{0u,0u},{0u,0u},{0u,0u}};
        const int qp = (lane >> 2) & 3;
#pragma unroll
        for (int mi = 0; mi < 4; ++mi) {
#pragma unroll
            for (int r = 0; r < 4; ++r) {
                bool act = ((lane >> 4) == mi) && ((lane & 3) == r);
#pragma unroll
                for (int th = 0; th < 3; ++th) {
                    unsigned long long b0 = __ballot(fabsf(acc[mi][0][r]) > T[th]);
                    unsigned long long b1 = __ballot(fabsf(acc[mi][1][r]) > T[th]);
                    unsigned long long b2 = __ballot(fabsf(acc[mi][2][r]) > T[th]);
                    unsigned long long b3 = __ballot(fabsf(acc[mi][3][r]) > T[th]);
                    if (act) {
                        wout[th][0] = ((unsigned)(b0 >> (qp * 16)) & 0xFFFFu)
                                    | (((unsigned)(b1 >> (qp * 16)) & 0xFFFFu) << 16);
                        wout[th][1] = ((unsigned)(b2 >> (qp * 16)) & 0xFFFFu)
                                    | (((unsigned)(b3 >> (qp * 16)) & 0xFFFFu) << 16);
                    }
                }
            }
        }

        const int grow    = i0 + wi * 64 + lane;
        const int colbase = j0 + wj * 64;
        unsigned int dd = (unsigned int)(grow - colbase);
        if (dd < 64u) {
            unsigned int m0 = (dd < 32u) ? ~(1u << dd) : 0xFFFFFFFFu;
            unsigned int m1 = (dd >= 32u) ? ~(1u << (dd - 32u)) : 0xFFFFFFFFu;
#pragma unroll
            for (int th = 0; th < 3; ++th) { wout[th][0] &= m0; wout[th][1] &= m1; }
        }
        const int wb = colbase >> 5;
        const size_t stride_t = (size_t)NBATCH * NASSETS * NWORDS;
        size_t rb = ((size_t)b * NASSETS + grow) * NWORDS + wb;
#pragma unroll
        for (int th = 0; th < 3; ++th) {
            adj[rb + th * stride_t]     = wout[th][0];
            adj[rb + th * stride_t + 1] = wout[th][1];
        }
    }

    // ---- grid barrier 1 (release adj, acquire for CC reads) ----
    __syncthreads();
    if (t == 0) {
        __threadfence();
        __hip_atomic_fetch_add(&bar[1], 1, __ATOMIC_RELEASE, __HIP_MEMORY_SCOPE_AGENT);
        while (__hip_atomic_load(&bar[1], __ATOMIC_ACQUIRE, __HIP_MEMORY_SCOPE_AGENT) < NBLK)
            __builtin_amdgcn_s_sleep(2);
        __threadfence();
    }
    __syncthreads();

    // ================= phase 2: connected components + betti (blocks 0..95) ======
    if (blk < 3 * NBATCH) {
        const int th = blk >> 5;
        const int b  = blk & 31;
        const int n1 = t + 256;

        const unsigned int* rp =
            adj + (((size_t)th * NBATCH + b) * NASSETS + t) * NWORDS;
        unsigned int rowA[NWORDS], rowB[NWORDS];
        int deg = 0;
#pragma unroll
        for (int w = 0; w < NWORDS; ++w) {
            rowA[w] = rp[w];
            rowB[w] = rp[256 * NWORDS + w];
            deg += __popc(rowA[w]) + __popc(rowB[w]);
        }

        int v = deg;
#pragma unroll
        for (int off = 32; off > 0; off >>= 1) v += __shfl_down(v, off);
        if (lane == 0) red[wave] = v;
        lab[t]  = t;
        lab[n1] = n1;
        __syncthreads();
        int total_deg = 0;
        if (t == 0)
            for (int k = 0; k < 4; ++k) total_deg += red[k];

        // min-label propagation + pointer jumping (monotone -> terminates)
        for (;;) {
            __syncthreads();
            if (t == 0) changed = 0;
            __syncthreads();
            int m0 = lab[t];
            int m1 = lab[n1];
#pragma unroll
            for (int w = 0; w < NWORDS; ++w) {
                unsigned int bits = rowA[w];
                int basej = w * 32;
                while (bits) {
                    int j = basej + __builtin_ctz(bits);
                    bits &= bits - 1;
                    int lj = lab[j];
                    if (lj < m0) m0 = lj;
                }
                bits = rowB[w];
                while (bits) {
                    int j = basej + __builtin_ctz(bits);
                    bits &= bits - 1;
                    int lj = lab[j];
                    if (lj < m1) m1 = lj;
                }
            }
            int lm0 = lab[m0]; if (lm0 < m0) m0 = lm0;
            int lm1 = lab[m1]; if (lm1 < m1) m1 = lm1;
            __syncthreads();
            if (m0 < lab[t])  { lab[t]  = m0; changed = 1; }
            if (m1 < lab[n1]) { lab[n1] = m1; changed = 1; }
            __syncthreads();
            if (!changed) break;
        }

        int isrep = ((lab[t] == t) ? 1 : 0) + ((lab[n1] == n1) ? 1 : 0);
#pragma unroll
        for (int off = 32; off > 0; off >>= 1) isrep += __shfl_down(isrep, off);
        __syncthreads();
        if (lane == 0) red[wave] = isrep;
        __syncthreads();
        if (t == 0) {
            int comps = 0;
            for (int k = 0; k < 4; ++k) comps += red[k];
            float compf = (float)comps;
            float edges = (float)total_deg * 0.5f;
            out[b * 6 + th * 2 + 0] = compf / (float)NASSETS;
            out[b * 6 + th * 2 + 1] = fmaxf(0.0f, edges - (float)NASSETS + compf) / (float)NASSETS;
        }
    }
}

extern "C" void kernel_launch(void* const* d_in, const int* in_sizes, int n_in,
                              void* d_out, int out_size, void* d_ws, size_t ws_size,
                              hipStream_t stream) {
    const float* ret = (const float*)d_in[0];
    float* out = (float*)d_out;
    char* ws = (char*)d_ws;

    char* Xt = ws;                                                    // 4 MB fp8
    unsigned int* adj =
        (unsigned int*)(ws + (size_t)NBATCH * NASSETS * WINDOW);      // 3 MB
    int* bar = (int*)(ws + (8u << 20));                               // 2 counters @ +8MB

    hipMemsetAsync(bar, 0, 2 * sizeof(int), stream);   // ws is 0xAA-poisoned pre-launch
    fused_topo_kernel<<<NBLK, 256, 0, stream>>>(ret, Xt, adj, bar, out);
}

// Round 7
// 94.382 us; speedup vs baseline: 2.3284x; 2.3284x over previous
//
#include <hip/hip_runtime.h>
#include <hip/hip_bf16.h>
#include <stdint.h>

#define NASSETS 512
#define WINDOW  256
#define NBATCH  32
#define NWORDS  16      // 512 bits / 32
#define BM 128
#define BN 128

typedef __attribute__((ext_vector_type(4))) float floatx4;
typedef __attribute__((ext_vector_type(4))) int   intx4;
typedef __attribute__((ext_vector_type(2))) long  longx2;

// ---- fp32 -> OCP e4m3fn (validated R4/R5: absmax=0) ----
__device__ __forceinline__ unsigned int f2e4m3_manual(float x) {
    union { float f; unsigned u; } c; c.f = x;
    unsigned s = (c.u >> 24) & 0x80u;
    unsigned a = c.u & 0x7FFFFFFFu;
    float af = fabsf(x);
    unsigned code;
    if (af >= 448.f) code = 0x7Eu;
    else if (af < 0.015625f) {
        code = (unsigned)(int)rintf(af * 512.f);
    } else {
        unsigned E = a >> 23;
        unsigned base = ((E - 120u) << 3) | ((a >> 20) & 7u);
        unsigned rem = a & 0xFFFFFu;
        if (rem > 0x80000u || (rem == 0x80000u && (base & 1u))) base++;
        if (base > 0x7Eu) base = 0x7Eu;
        code = base;
    }
    return s | code;
}

__device__ __forceinline__ int pack4fp8(float f0, float f1, float f2, float f3) {
#if defined(__has_builtin) && __has_builtin(__builtin_amdgcn_cvt_pk_fp8_f32)
    int v = 0;
    v = __builtin_amdgcn_cvt_pk_fp8_f32(f0, f1, v, false);
    v = __builtin_amdgcn_cvt_pk_fp8_f32(f2, f3, v, true);
    return v;
#else
    return (int)(f2e4m3_manual(f0) | (f2e4m3_manual(f1) << 8) |
                 (f2e4m3_manual(f2) << 16) | (f2e4m3_manual(f3) << 24));
#endif
}

// async global->LDS, 16B/lane; LDS dst wave-uniform base + lane*16
__device__ __forceinline__ void gload16(const void* gp, void* lp) {
    __builtin_amdgcn_global_load_lds(
        (const __attribute__((address_space(1))) void*)(uintptr_t)gp,
        (__attribute__((address_space(3))) void*)(unsigned int)(uintptr_t)lp,
        16, 0, 0);
}

// Kernel 1 (R5-validated, unchanged): fused single-read normalize + transpose ->
// fp8 Xt[b][n][256B row], rows pre-interleaved per 64-k slab for corr staging.
__global__ __launch_bounds__(512)
void normalize_kernel(const float* __restrict__ ret, char* __restrict__ Xt) {
    __shared__ float sred[512];
    __shared__ float ssred[512];
    __shared__ float smean[64];
    __shared__ float sinv[64];
    __shared__ __align__(16) char tile[64 * 256];  // 16 KB; row a: 16 slots, slot L at L^(a&15)

    const int t  = threadIdx.x;
    const int a  = t & 63;
    const int wc = t >> 6;                 // 0..7, 32 w's each
    const int g  = blockIdx.x;
    const int b  = blockIdx.y;
    const int n0 = g * 64;

    const float* base = ret + (size_t)b * WINDOW * NASSETS + n0 + a;

    float x[32];
    float s1 = 0.f, s2 = 0.f;
#pragma unroll
    for (int k = 0; k < 32; ++k) {
        x[k] = base[(size_t)(wc * 32 + k) * NASSETS];
        s1 += x[k];
        s2 += x[k] * x[k];
    }
    sred[wc * 64 + a]  = s1;
    ssred[wc * 64 + a] = s2;
    __syncthreads();

    if (t < 64) {
        float S = 0.f, S2 = 0.f;
#pragma unroll
        for (int c = 0; c < 8; ++c) { S += sred[c * 64 + t]; S2 += ssred[c * 64 + t]; }
        float mean = S / (float)WINDOW;
        float var  = (S2 - (float)WINDOW * mean * mean) / (float)(WINDOW - 1);
        if (var < 0.f) var = 0.f;
        float stdv = sqrtf(var) + 1e-8f;   // ref: std(ddof=1) + 1e-8
        smean[t] = mean;
        sinv[t]  = 1.0f / stdv;
    }
    __syncthreads();

    const float mn = smean[a];
    const float iv = sinv[a];

    int pk[8];
#pragma unroll
    for (int j = 0; j < 8; ++j)
        pk[j] = pack4fp8((x[4*j+0] - mn) * iv, (x[4*j+1] - mn) * iv,
                         (x[4*j+2] - mn) * iv, (x[4*j+3] - mn) * iv);

    char* rowp = tile + a * 256;
    const int s  = wc >> 1;
    const int h8 = (wc & 1) * 8;
#pragma unroll
    for (int q = 0; q < 4; ++q) {
        unsigned long long piece = (unsigned)pk[2*q] |
                                   ((unsigned long long)(unsigned)pk[2*q+1] << 32);
        int L = s * 4 + q;
        *(unsigned long long*)(rowp + ((L ^ (a & 15)) * 16) + h8) = piece;
    }
    __syncthreads();

    char* orow = Xt + ((size_t)b * NASSETS + n0) * WINDOW;
#pragma unroll
    for (int it = 0; it < 2; ++it) {
        int idx = it * 512 + t;
        int r  = idx >> 4;
        int sl = idx & 15;
        intx4 v = *(const intx4*)(tile + r * 256 + ((sl ^ (r & 15)) * 16));
        *(intx4*)(orow + r * WINDOW + sl * 16) = v;
    }
}

// Kernel 2: corr (fp8 MFMA, R5-validated) + ticket -> last block per batch runs CC.
// grid (4 jt, 4 it, 32 b) = 512 blocks, block 256. adj words stored as relaxed
// AGENT-scope atomic stores (coherent across XCDs); ticket add ACQ_REL orders them.
__global__ __launch_bounds__(256)
void corr_cc_kernel(const char* __restrict__ Xt, unsigned int* __restrict__ adj,
                    int* __restrict__ cnt, float* __restrict__ out) {
    __shared__ __align__(16) char lsA[BM * 64];   // 8 KB
    __shared__ __align__(16) char lsB[BN * 64];   // 8 KB
    __shared__ int lab[NASSETS];
    __shared__ int red[4];
    __shared__ int changed;
    __shared__ int isLast;

    const int t    = threadIdx.x;
    const int lane = t & 63;
    const int wave = t >> 6;
    const int wi   = wave >> 1, wj = wave & 1;
    const int b  = blockIdx.z;
    const int i0 = blockIdx.y * BM;
    const int j0 = blockIdx.x * BN;

    const char* base = Xt + (size_t)b * NASSETS * WINDOW;

    const int m  = lane & 15;
    const int kq = lane >> 4;
    const int srowAdd  = lane >> 2;
    const int gslotOff = ((lane & 3) ^ ((lane >> 2) & 3)) * 16;

    floatx4 acc[4][4] = {};

    for (int k0 = 0; k0 < WINDOW; k0 += 64) {
        __syncthreads();
#pragma unroll
        for (int c = 0; c < 2; ++c) {
            int r0 = (wave * 2 + c) * 16;
            const char* gA = base + (size_t)(i0 + r0 + srowAdd) * WINDOW + k0 + gslotOff;
            const char* gB = base + (size_t)(j0 + r0 + srowAdd) * WINDOW + k0 + gslotOff;
            gload16(gA, (char*)lsA + r0 * 64);
            gload16(gB, (char*)lsB + r0 * 64);
        }
        __syncthreads();

        longx2 af[4], bf[4];
#pragma unroll
        for (int mi = 0; mi < 4; ++mi) {
            int r = wi * 64 + mi * 16 + m;
            af[mi] = *(const longx2*)(lsA + r * 64 + ((kq ^ (r & 3)) * 16));
        }
#pragma unroll
        for (int nj = 0; nj < 4; ++nj) {
            int r = wj * 64 + nj * 16 + m;
            bf[nj] = *(const longx2*)(lsB + r * 64 + ((kq ^ (r & 3)) * 16));
        }
#pragma unroll
        for (int mi = 0; mi < 4; ++mi)
#pragma unroll
            for (int nj = 0; nj < 4; ++nj) {
                acc[mi][nj] = __builtin_amdgcn_mfma_f32_16x16x32_fp8_fp8(
                    af[mi].x, bf[nj].x, acc[mi][nj], 0, 0, 0);
                acc[mi][nj] = __builtin_amdgcn_mfma_f32_16x16x32_fp8_fp8(
                    af[mi].y, bf[nj].y, acc[mi][nj], 0, 0, 0);
            }
    }

    // Ballot bit-pack epilogue (validated R2-R6). C/D: col=lane&15, row=(lane>>4)*4+r.
    const float T[3] = {0.3f * (float)WINDOW, 0.5f * (float)WINDOW, 0.7f * (float)WINDOW};
    unsigned int wout[3][2] = {{0u,0u},{0u,0u},{0u,0u}};
    const int qp = (lane >> 2) & 3;
#pragma unroll
    for (int mi = 0; mi < 4; ++mi) {
#pragma unroll
        for (int r = 0; r < 4; ++r) {
            bool act = ((lane >> 4) == mi) && ((lane & 3) == r);
#pragma unroll
            for (int th = 0; th < 3; ++th) {
                unsigned long long b0 = __ballot(fabsf(acc[mi][0][r]) > T[th]);
                unsigned long long b1 = __ballot(fabsf(acc[mi][1][r]) > T[th]);
                unsigned long long b2 = __ballot(fabsf(acc[mi][2][r]) > T[th]);
                unsigned long long b3 = __ballot(fabsf(acc[mi][3][r]) > T[th]);
                if (act) {
                    wout[th][0] = ((unsigned)(b0 >> (qp * 16)) & 0xFFFFu)
                                | (((unsigned)(b1 >> (qp * 16)) & 0xFFFFu) << 16);
                    wout[th][1] = ((unsigned)(b2 >> (qp * 16)) & 0xFFFFu)
                                | (((unsigned)(b3 >> (qp * 16)) & 0xFFFFu) << 16);
                }
            }
        }
    }

    const int grow    = i0 + wi * 64 + lane;
    const int colbase = j0 + wj * 64;
    unsigned int dd = (unsigned int)(grow - colbase);
    if (dd < 64u) {
        unsigned int m0 = (dd < 32u) ? ~(1u << dd) : 0xFFFFFFFFu;
        unsigned int m1 = (dd >= 32u) ? ~(1u << (dd - 32u)) : 0xFFFFFFFFu;
#pragma unroll
        for (int th = 0; th < 3; ++th) { wout[th][0] &= m0; wout[th][1] &= m1; }
    }
    const int wb = colbase >> 5;
    const size_t stride_t = (size_t)NBATCH * NASSETS * NWORDS;
    size_t rb = ((size_t)b * NASSETS + grow) * NWORDS + wb;
#pragma unroll
    for (int th = 0; th < 3; ++th) {
        // coherent (agent-scope) stores: visible cross-XCD without any L2 writeback fence
        __hip_atomic_store(&adj[rb + th * stride_t],     wout[th][0],
                           __ATOMIC_RELAXED, __HIP_MEMORY_SCOPE_AGENT);
        __hip_atomic_store(&adj[rb + th * stride_t + 1], wout[th][1],
                           __ATOMIC_RELAXED, __HIP_MEMORY_SCOPE_AGENT);
    }

    // ---- ticket: 16th arriver for this batch runs CC inline ----
    __syncthreads();   // drains vmcnt(0) for ALL waves -> all stores at coherent point
    if (t == 0) {
        int old = __hip_atomic_fetch_add(&cnt[b], 1, __ATOMIC_ACQ_REL,
                                         __HIP_MEMORY_SCOPE_AGENT);
        isLast = (old == 15) ? 1 : 0;
    }
    __syncthreads();   // isLast visible; acquire-inv (by wave0) precedes all reads
    if (!isLast) return;

    // ================= CC + betti for batch b (R6-validated 256-thread body) =====
    const int n1 = t + 256;
    for (int th = 0; th < 3; ++th) {
        __syncthreads();
        const unsigned int* rp =
            adj + (((size_t)th * NBATCH + b) * NASSETS + t) * NWORDS;
        unsigned int rowA[NWORDS], rowB[NWORDS];
        int deg = 0;
#pragma unroll
        for (int w = 0; w < NWORDS; ++w) {
            rowA[w] = rp[w];
            rowB[w] = rp[256 * NWORDS + w];
            deg += __popc(rowA[w]) + __popc(rowB[w]);
        }

        int v = deg;
#pragma unroll
        for (int off = 32; off > 0; off >>= 1) v += __shfl_down(v, off);
        if (lane == 0) red[wave] = v;
        lab[t]  = t;
        lab[n1] = n1;
        __syncthreads();
        int total_deg = 0;
        if (t == 0)
            for (int k = 0; k < 4; ++k) total_deg += red[k];

        for (;;) {
            __syncthreads();
            if (t == 0) changed = 0;
            __syncthreads();
            int m0 = lab[t];
            int m1 = lab[n1];
#pragma unroll
            for (int w = 0; w < NWORDS; ++w) {
                unsigned int bits = rowA[w];
                int basej = w * 32;
                while (bits) {
                    int j = basej + __builtin_ctz(bits);
                    bits &= bits - 1;
                    int lj = lab[j];
                    if (lj < m0) m0 = lj;
                }
                bits = rowB[w];
                while (bits) {
                    int j = basej + __builtin_ctz(bits);
                    bits &= bits - 1;
                    int lj = lab[j];
                    if (lj < m1) m1 = lj;
                }
            }
            int lm0 = lab[m0]; if (lm0 < m0) m0 = lm0;
            int lm1 = lab[m1]; if (lm1 < m1) m1 = lm1;
            __syncthreads();
            if (m0 < lab[t])  { lab[t]  = m0; changed = 1; }
            if (m1 < lab[n1]) { lab[n1] = m1; changed = 1; }
            __syncthreads();
            if (!changed) break;
        }

        int isrep = ((lab[t] == t) ? 1 : 0) + ((lab[n1] == n1) ? 1 : 0);
#pragma unroll
        for (int off = 32; off > 0; off >>= 1) isrep += __shfl_down(isrep, off);
        __syncthreads();
        if (lane == 0) red[wave] = isrep;
        __syncthreads();
        if (t == 0) {
            int comps = 0;
            for (int k = 0; k < 4; ++k) comps += red[k];
            float compf = (float)comps;
            float edges = (float)total_deg * 0.5f;
            out[b * 6 + th * 2 + 0] = compf / (float)NASSETS;
            out[b * 6 + th * 2 + 1] = fmaxf(0.0f, edges - (float)NASSETS + compf) / (float)NASSETS;
        }
    }
}

extern "C" void kernel_launch(void* const* d_in, const int* in_sizes, int n_in,
                              void* d_out, int out_size, void* d_ws, size_t ws_size,
                              hipStream_t stream) {
    const float* ret = (const float*)d_in[0];
    float* out = (float*)d_out;
    char* ws = (char*)d_ws;

    char* Xt = ws;                                                    // 4 MB fp8
    unsigned int* adj =
        (unsigned int*)(ws + (size_t)NBATCH * NASSETS * WINDOW);      // 3 MB
    int* cnt = (int*)(ws + (8u << 20));                               // 32 tickets @ +8MB

    hipMemsetAsync(cnt, 0, NBATCH * sizeof(int), stream);             // ws is 0xAA-poisoned

    dim3 g1(NASSETS / 64, NBATCH);
    normalize_kernel<<<g1, 512, 0, stream>>>(ret, Xt);

    dim3 g2(NASSETS / BN, NASSETS / BM, NBATCH);
    corr_cc_kernel<<<g2, 256, 0, stream>>>(Xt, adj, cnt, out);
}

// Round 8
// 77.863 us; speedup vs baseline: 2.8224x; 1.2122x over previous
//
#include <hip/hip_runtime.h>
#include <hip/hip_bf16.h>
#include <stdint.h>

#define NASSETS 512
#define WINDOW  256
#define NBATCH  32
#define NWORDS  16      // 512 bits / 32
#define BM 128
#define BN 128

typedef __attribute__((ext_vector_type(4))) float floatx4;
typedef __attribute__((ext_vector_type(4))) int   intx4;
typedef __attribute__((ext_vector_type(2))) long  longx2;

// ---- fp32 -> OCP e4m3fn (validated R4-R7: absmax=0) ----
__device__ __forceinline__ unsigned int f2e4m3_manual(float x) {
    union { float f; unsigned u; } c; c.f = x;
    unsigned s = (c.u >> 24) & 0x80u;
    unsigned a = c.u & 0x7FFFFFFFu;
    float af = fabsf(x);
    unsigned code;
    if (af >= 448.f) code = 0x7Eu;
    else if (af < 0.015625f) {
        code = (unsigned)(int)rintf(af * 512.f);
    } else {
        unsigned E = a >> 23;
        unsigned base = ((E - 120u) << 3) | ((a >> 20) & 7u);
        unsigned rem = a & 0xFFFFFu;
        if (rem > 0x80000u || (rem == 0x80000u && (base & 1u))) base++;
        if (base > 0x7Eu) base = 0x7Eu;
        code = base;
    }
    return s | code;
}

__device__ __forceinline__ int pack4fp8(float f0, float f1, float f2, float f3) {
#if defined(__has_builtin) && __has_builtin(__builtin_amdgcn_cvt_pk_fp8_f32)
    int v = 0;
    v = __builtin_amdgcn_cvt_pk_fp8_f32(f0, f1, v, false);
    v = __builtin_amdgcn_cvt_pk_fp8_f32(f2, f3, v, true);
    return v;
#else
    return (int)(f2e4m3_manual(f0) | (f2e4m3_manual(f1) << 8) |
                 (f2e4m3_manual(f2) << 16) | (f2e4m3_manual(f3) << 24));
#endif
}

// async global->LDS, 16B/lane; LDS dst wave-uniform base + lane*16
__device__ __forceinline__ void gload16(const void* gp, void* lp) {
    __builtin_amdgcn_global_load_lds(
        (const __attribute__((address_space(1))) void*)(uintptr_t)gp,
        (__attribute__((address_space(3))) void*)(unsigned int)(uintptr_t)lp,
        16, 0, 0);
}

// Kernel 1 (v4): normalize re-tiled for 2x TLP: 256 blocks x 1024 threads =
// 4096 waves (4/SIMD, was 2/SIMD). Thread (a=t&63, wc=t>>6 in 0..15) holds 16
// floats of column n0+a; fp32 stats via LDS reduce; fp8 pack -> XOR-swizzled
// LDS tile -> coalesced transposed writeout. Row layout IDENTICAL to R5
// (4 slabs of 64 k; slot q of slab s = k[s*64+q*8..+7] ++ k[s*64+32+q*8..+7]).
__global__ __launch_bounds__(1024)
void normalize_kernel(const float* __restrict__ ret, char* __restrict__ Xt) {
    __shared__ float sred[1024];
    __shared__ float ssred[1024];
    __shared__ float smean[64];
    __shared__ float sinv[64];
    __shared__ __align__(16) char tile[64 * 256];  // 16 KB; row a: 16 slots, slot L at L^(a&15)

    const int t  = threadIdx.x;
    const int a  = t & 63;
    const int wc = t >> 6;                 // 0..15, 16 w's each
    const int g  = blockIdx.x;
    const int b  = blockIdx.y;
    const int n0 = g * 64;

    const float* base = ret + (size_t)b * WINDOW * NASSETS + n0 + a;

    float x[16];
    float s1 = 0.f, s2 = 0.f;
#pragma unroll
    for (int k = 0; k < 16; ++k) {
        x[k] = base[(size_t)(wc * 16 + k) * NASSETS];
        s1 += x[k];
        s2 += x[k] * x[k];
    }
    sred[wc * 64 + a]  = s1;
    ssred[wc * 64 + a] = s2;
    __syncthreads();

    if (t < 64) {
        float S = 0.f, S2 = 0.f;
#pragma unroll
        for (int c = 0; c < 16; ++c) { S += sred[c * 64 + t]; S2 += ssred[c * 64 + t]; }
        float mean = S / (float)WINDOW;
        float var  = (S2 - (float)WINDOW * mean * mean) / (float)(WINDOW - 1);
        if (var < 0.f) var = 0.f;
        float stdv = sqrtf(var) + 1e-8f;   // ref: std(ddof=1) + 1e-8
        smean[t] = mean;
        sinv[t]  = 1.0f / stdv;
    }
    __syncthreads();

    const float mn = smean[a];
    const float iv = sinv[a];

    int pk[4];
#pragma unroll
    for (int j = 0; j < 4; ++j)
        pk[j] = pack4fp8((x[4*j+0] - mn) * iv, (x[4*j+1] - mn) * iv,
                         (x[4*j+2] - mn) * iv, (x[4*j+3] - mn) * iv);

    // thread's 16 w = w[wc*16 .. +15]: slab s = wc>>2; o = (wc&3)*16;
    // o<32 -> first halves (h8=0) of slots qbase,qbase+1; o>=32 -> second halves;
    // qbase = (wc&1)*2
    char* rowp = tile + a * 256;
    const int s     = wc >> 2;
    const int h8    = (wc & 2) ? 8 : 0;
    const int qbase = (wc & 1) * 2;
#pragma unroll
    for (int q = 0; q < 2; ++q) {
        unsigned long long piece = (unsigned)pk[2*q] |
                                   ((unsigned long long)(unsigned)pk[2*q+1] << 32);
        int L = s * 4 + qbase + q;
        *(unsigned long long*)(rowp + ((L ^ (a & 15)) * 16) + h8) = piece;
    }
    __syncthreads();

    // writeout: 1024 16B segs, one per thread; wave covers 4 rows = 1 KB contiguous
    char* orow = Xt + ((size_t)b * NASSETS + n0) * WINDOW;
    {
        int r  = t >> 4;
        int sl = t & 15;
        intx4 v = *(const intx4*)(tile + r * 256 + ((sl ^ (r & 15)) * 16));
        *(intx4*)(orow + r * WINDOW + sl * 16) = v;
    }
}

// Kernel 2 (R5-validated, unchanged): 128x128 corr tile, fp8 MFMA, gload16
// staging, ballot bit-pack. grid (4 jt, 4 it, 32 b) = 512 blocks, block 256.
__global__ __launch_bounds__(256)
void corr_adj_kernel(const char* __restrict__ Xt, unsigned int* __restrict__ adj) {
    __shared__ __align__(16) char lsA[BM * 64];   // 8 KB
    __shared__ __align__(16) char lsB[BN * 64];   // 8 KB

    const int t    = threadIdx.x;
    const int lane = t & 63;
    const int wave = t >> 6;
    const int wi   = wave >> 1, wj = wave & 1;
    const int b  = blockIdx.z;
    const int i0 = blockIdx.y * BM;
    const int j0 = blockIdx.x * BN;

    const char* base = Xt + (size_t)b * NASSETS * WINDOW;

    const int m  = lane & 15;
    const int kq = lane >> 4;
    const int srowAdd  = lane >> 2;
    const int gslotOff = ((lane & 3) ^ ((lane >> 2) & 3)) * 16;

    floatx4 acc[4][4] = {};

    for (int k0 = 0; k0 < WINDOW; k0 += 64) {
        __syncthreads();
#pragma unroll
        for (int c = 0; c < 2; ++c) {
            int r0 = (wave * 2 + c) * 16;
            const char* gA = base + (size_t)(i0 + r0 + srowAdd) * WINDOW + k0 + gslotOff;
            const char* gB = base + (size_t)(j0 + r0 + srowAdd) * WINDOW + k0 + gslotOff;
            gload16(gA, (char*)lsA + r0 * 64);
            gload16(gB, (char*)lsB + r0 * 64);
        }
        __syncthreads();

        longx2 af[4], bf[4];
#pragma unroll
        for (int mi = 0; mi < 4; ++mi) {
            int r = wi * 64 + mi * 16 + m;
            af[mi] = *(const longx2*)(lsA + r * 64 + ((kq ^ (r & 3)) * 16));
        }
#pragma unroll
        for (int nj = 0; nj < 4; ++nj) {
            int r = wj * 64 + nj * 16 + m;
            bf[nj] = *(const longx2*)(lsB + r * 64 + ((kq ^ (r & 3)) * 16));
        }
#pragma unroll
        for (int mi = 0; mi < 4; ++mi)
#pragma unroll
            for (int nj = 0; nj < 4; ++nj) {
                acc[mi][nj] = __builtin_amdgcn_mfma_f32_16x16x32_fp8_fp8(
                    af[mi].x, bf[nj].x, acc[mi][nj], 0, 0, 0);
                acc[mi][nj] = __builtin_amdgcn_mfma_f32_16x16x32_fp8_fp8(
                    af[mi].y, bf[nj].y, acc[mi][nj], 0, 0, 0);
            }
    }

    // Ballot bit-pack epilogue (validated). C/D: col=lane&15, row=(lane>>4)*4+r.
    const float T[3] = {0.3f * (float)WINDOW, 0.5f * (float)WINDOW, 0.7f * (float)WINDOW};
    unsigned int wout[3][2] = {{0u,0u},{0u,0u},{0u,0u}};
    const int qp = (lane >> 2) & 3;
#pragma unroll
    for (int mi = 0; mi < 4; ++mi) {
#pragma unroll
        for (int r = 0; r < 4; ++r) {
            bool act = ((lane >> 4) == mi) && ((lane & 3) == r);
#pragma unroll
            for (int th = 0; th < 3; ++th) {
                unsigned long long b0 = __ballot(fabsf(acc[mi][0][r]) > T[th]);
                unsigned long long b1 = __ballot(fabsf(acc[mi][1][r]) > T[th]);
                unsigned long long b2 = __ballot(fabsf(acc[mi][2][r]) > T[th]);
                unsigned long long b3 = __ballot(fabsf(acc[mi][3][r]) > T[th]);
                if (act) {
                    wout[th][0] = ((unsigned)(b0 >> (qp * 16)) & 0xFFFFu)
                                | (((unsigned)(b1 >> (qp * 16)) & 0xFFFFu) << 16);
                    wout[th][1] = ((unsigned)(b2 >> (qp * 16)) & 0xFFFFu)
                                | (((unsigned)(b3 >> (qp * 16)) & 0xFFFFu) << 16);
                }
            }
        }
    }

    const int grow    = i0 + wi * 64 + lane;
    const int colbase = j0 + wj * 64;
    unsigned int dd = (unsigned int)(grow - colbase);
    if (dd < 64u) {
        unsigned int m0 = (dd < 32u) ? ~(1u << dd) : 0xFFFFFFFFu;
        unsigned int m1 = (dd >= 32u) ? ~(1u << (dd - 32u)) : 0xFFFFFFFFu;
#pragma unroll
        for (int th = 0; th < 3; ++th) { wout[th][0] &= m0; wout[th][1] &= m1; }
    }
    const int wb = colbase >> 5;
    const size_t stride_t = (size_t)NBATCH * NASSETS * NWORDS;
    size_t rb = ((size_t)b * NASSETS + grow) * NWORDS + wb;
#pragma unroll
    for (int th = 0; th < 3; ++th) {
        adj[rb + th * stride_t]     = wout[th][0];
        adj[rb + th * stride_t + 1] = wout[th][1];
    }
}

// Kernel 3 (R5-validated, unchanged): CC (min-label + pointer jumping) + edges.
__global__ __launch_bounds__(512)
void betti_kernel(const unsigned int* __restrict__ adj, float* __restrict__ out) {
    __shared__ int lab[NASSETS];
    __shared__ int changed;
    __shared__ int red[8];

    int th = blockIdx.x;
    int b  = blockIdx.y;
    int i  = threadIdx.x;
    int lane = i & 63, wv = i >> 6;

    const unsigned int* rowp =
        adj + (((size_t)th * NBATCH + b) * NASSETS + i) * NWORDS;
    unsigned int row[NWORDS];
    int deg = 0;
#pragma unroll
    for (int w = 0; w < NWORDS; ++w) {
        row[w] = rowp[w];
        deg += __popc(row[w]);
    }

    int v = deg;
#pragma unroll
    for (int off = 32; off > 0; off >>= 1) v += __shfl_down(v, off);
    if (lane == 0) red[wv] = v;
    lab[i] = i;
    __syncthreads();
    int total_deg = 0;
    if (i == 0)
        for (int k = 0; k < 8; ++k) total_deg += red[k];

    for (;;) {
        __syncthreads();
        if (i == 0) changed = 0;
        __syncthreads();
        int mlab = lab[i];
#pragma unroll
        for (int w = 0; w < NWORDS; ++w) {
            unsigned int bits = row[w];
            int basej = w * 32;
            while (bits) {
                int j = basej + __builtin_ctz(bits);
                bits &= bits - 1;
                int lj = lab[j];
                if (lj < mlab) mlab = lj;
            }
        }
        int lm = lab[mlab];
        if (lm < mlab) mlab = lm;
        __syncthreads();
        if (mlab < lab[i]) { lab[i] = mlab; changed = 1; }
        __syncthreads();
        if (!changed) break;
    }

    int isrep = (lab[i] == i) ? 1 : 0;
#pragma unroll
    for (int off = 32; off > 0; off >>= 1) isrep += __shfl_down(isrep, off);
    if (lane == 0) red[wv] = isrep;
    __syncthreads();
    if (i == 0) {
        int comps = 0;
        for (int k = 0; k < 8; ++k) comps += red[k];
        float compf = (float)comps;
        float edges = (float)total_deg * 0.5f;
        out[b * 6 + th * 2 + 0] = compf / (float)NASSETS;
        out[b * 6 + th * 2 + 1] = fmaxf(0.0f, edges - (float)NASSETS + compf) / (float)NASSETS;
    }
}

extern "C" void kernel_launch(void* const* d_in, const int* in_sizes, int n_in,
                              void* d_out, int out_size, void* d_ws, size_t ws_size,
                              hipStream_t stream) {
    const float* ret = (const float*)d_in[0];
    float* out = (float*)d_out;
    char* ws = (char*)d_ws;

    char* Xt = ws;                                                    // 4 MB fp8
    unsigned int* adj =
        (unsigned int*)(ws + (size_t)NBATCH * NASSETS * WINDOW);      // 3 MB

    dim3 g1(NASSETS / 64, NBATCH);
    normalize_kernel<<<g1, 1024, 0, stream>>>(ret, Xt);

    dim3 g2(NASSETS / BN, NASSETS / BM, NBATCH);
    corr_adj_kernel<<<g2, 256, 0, stream>>>(Xt, adj);

    dim3 g3(3, NBATCH);
    betti_kernel<<<g3, 512, 0, stream>>>(adj, out);
}